// Round 2
// baseline (976.916 us; speedup 1.0000x reference)
//
#include <hip/hip_runtime.h>
#include <hip/hip_bf16.h>
#include <math.h>

#define N_IN 28
#define N_MID 256
#define N_OUT 28
#define SEQ 28
#define BATCH 4096
#define G3 768

#define M_ROWS 32
#define THREADS 512
#define NBLK (BATCH / M_ROWS)   // 128

typedef __attribute__((ext_vector_type(8))) short bf16x8;
typedef __attribute__((ext_vector_type(4))) float f32x4;

#define MFMA(a, b, c) __builtin_amdgcn_mfma_f32_16x16x32_bf16((a), (b), (c), 0, 0, 0)

__device__ __forceinline__ short f2bf(float v) {
    __hip_bfloat16 b = __float2bfloat16(v);
    return *reinterpret_cast<short*>(&b);
}
__device__ __forceinline__ float bf2f(short s) {
    unsigned int u = ((unsigned int)(unsigned short)s) << 16;
    return __uint_as_float(u);
}
__device__ __forceinline__ float fsigmoid(float v) {
    return 1.0f / (1.0f + __expf(-v));
}
__device__ __forceinline__ float ftanh(float v) {
    float e = __expf(2.0f * v);
    return 1.0f - 2.0f / (e + 1.0f);
}

// prep: w_hh [768][256] f32 -> wB bf16 [768][256]; w_ih [768][28] -> wI bf16 [768][32] zero-padded
__global__ void prep_w(const float* __restrict__ w_hh, const float* __restrict__ w_ih,
                       short* __restrict__ wB, short* __restrict__ wI) {
    int idx = blockIdx.x * 256 + threadIdx.x;
    if (idx < G3 * N_MID) wB[idx] = f2bf(w_hh[idx]);
    if (idx < G3 * 32) {
        int g = idx >> 5, k = idx & 31;
        float v = (k < N_IN) ? w_ih[g * N_IN + k] : 0.0f;
        wI[idx] = f2bf(v);
    }
}

__global__ __launch_bounds__(THREADS, 2) void gru_mfma(
    const float* __restrict__ x,     // [B][T][N_IN]
    const short* __restrict__ wB,    // [768][256] bf16
    const short* __restrict__ wI,    // [768][32] bf16
    const float* __restrict__ b_ih,
    const float* __restrict__ b_hh,
    const float* __restrict__ fc_w,  // [28][256]
    const float* __restrict__ fc_b,  // [28]
    float* __restrict__ out)         // [B][28]
{
    // [buf][prec hi/lo][half][chunk][row][8]  — A-fragment layout, 16B units contiguous
    __shared__ short hfrag[2][2][2][32][16][8];   // 64 KB
    __shared__ short xfrag[2][2][2][4][16][8];    // 8 KB

    const int tid  = threadIdx.x;
    const int lane = tid & 63;
    const int wv   = tid >> 6;      // 0..7
    const int wm   = wv >> 2;       // row half 0..1
    const int wn   = wv & 3;        // col quarter 0..3
    const int l15  = lane & 15;
    const int lg   = lane >> 4;     // 0..3
    const int rowbase = blockIdx.x * M_ROWS;

    // zero hfrag buf0 (h(t=0) = 0)
    {
        int* p = (int*)&hfrag[0][0][0][0][0][0];
        #pragma unroll
        for (int i = 0; i < 16; ++i) p[tid + i * THREADS] = 0;
    }

    // stage x for t=0 into xfrag[0]
    {
        #pragma unroll
        for (int it = 0; it < 2; ++it) {
            int q = tid + it * THREADS;                 // 0..1023
            int half = q >> 9, rem = q & 511;
            int chunk = rem >> 7, row16 = (rem >> 3) & 15, pos = rem & 7;
            int i = chunk * 8 + pos;
            int row = half * 16 + row16;
            float v = 0.0f;
            if (i < N_IN) v = x[(size_t)(rowbase + row) * (SEQ * N_IN) + 0 * N_IN + i];
            short hi = f2bf(v);
            short lo = f2bf(v - bf2f(hi));
            xfrag[0][0][half][chunk][row16][pos] = hi;
            xfrag[0][1][half][chunk][row16][pos] = lo;
        }
    }

    // per-lane column set and biases
    int   col[4];
    float bR[4], bZ[4], bIN[4], bHN[4];
    #pragma unroll
    for (int s = 0; s < 4; ++s) {
        int c = 64 * wn + 16 * s + l15;
        col[s] = c;
        bR[s]  = b_ih[c]       + b_hh[c];
        bZ[s]  = b_ih[256 + c] + b_hh[256 + c];
        bIN[s] = b_ih[512 + c];
        bHN[s] = b_hh[512 + c];
    }

    // loop-invariant B-operand pointers (element units)
    const short* pB[3][4];
    const short* pI[3][4];
    #pragma unroll
    for (int g = 0; g < 3; ++g)
        #pragma unroll
        for (int s = 0; s < 4; ++s) {
            int cc = g * 256 + col[s];
            pB[g][s] = wB + cc * 256 + lg * 8;
            pI[g][s] = wI + cc * 32  + lg * 8;
        }

    float hold[4][4];
    #pragma unroll
    for (int s = 0; s < 4; ++s)
        #pragma unroll
        for (int j = 0; j < 4; ++j) hold[s][j] = 0.0f;

    for (int t = 0; t < SEQ; ++t) {
        __syncthreads();
        const int rb = t & 1, wbuf = rb ^ 1;

        f32x4 aR[4], aZ[4], aIN[4], aHN[4];
        #pragma unroll
        for (int s = 0; s < 4; ++s) {
            aR[s]  = (f32x4){bR[s],  bR[s],  bR[s],  bR[s]};
            aZ[s]  = (f32x4){bZ[s],  bZ[s],  bZ[s],  bZ[s]};
            aIN[s] = (f32x4){bIN[s], bIN[s], bIN[s], bIN[s]};
            aHN[s] = (f32x4){bHN[s], bHN[s], bHN[s], bHN[s]};
        }

        // ---- input projection (one K=32 step)
        {
            bf16x8 xh = *(const bf16x8*)&xfrag[rb][0][wm][lg][l15][0];
            bf16x8 xl = *(const bf16x8*)&xfrag[rb][1][wm][lg][l15][0];
            #pragma unroll
            for (int s = 0; s < 4; ++s) {
                bf16x8 b0 = *(const bf16x8*)pI[0][s];
                aR[s]  = MFMA(xh, b0, aR[s]);  aR[s]  = MFMA(xl, b0, aR[s]);
                bf16x8 b1 = *(const bf16x8*)pI[1][s];
                aZ[s]  = MFMA(xh, b1, aZ[s]);  aZ[s]  = MFMA(xl, b1, aZ[s]);
                bf16x8 b2 = *(const bf16x8*)pI[2][s];
                aIN[s] = MFMA(xh, b2, aIN[s]); aIN[s] = MFMA(xl, b2, aIN[s]);
            }
        }

        // ---- hidden projection, K=256 over 8 ksteps
        #pragma unroll
        for (int ks = 0; ks < 8; ++ks) {
            bf16x8 ah = *(const bf16x8*)&hfrag[rb][0][wm][4 * ks + lg][l15][0];
            bf16x8 al = *(const bf16x8*)&hfrag[rb][1][wm][4 * ks + lg][l15][0];
            #pragma unroll
            for (int s = 0; s < 4; ++s) {
                bf16x8 b0 = *(const bf16x8*)(pB[0][s] + ks * 32);
                aR[s]  = MFMA(ah, b0, aR[s]);  aR[s]  = MFMA(al, b0, aR[s]);
                bf16x8 b1 = *(const bf16x8*)(pB[1][s] + ks * 32);
                aZ[s]  = MFMA(ah, b1, aZ[s]);  aZ[s]  = MFMA(al, b1, aZ[s]);
                bf16x8 b2 = *(const bf16x8*)(pB[2][s] + ks * 32);
                aHN[s] = MFMA(ah, b2, aHN[s]); aHN[s] = MFMA(al, b2, aHN[s]);
            }
        }

        // ---- lane-local GRU update; write next A-fragments
        #pragma unroll
        for (int s = 0; s < 4; ++s) {
            int c = col[s];
            #pragma unroll
            for (int j = 0; j < 4; ++j) {
                float r = fsigmoid(aR[s][j]);
                float z = fsigmoid(aZ[s][j]);
                float n = ftanh(aIN[s][j] + r * aHN[s][j]);
                float hnew = (1.0f - z) * n + z * hold[s][j];
                hold[s][j] = hnew;
                short hi = f2bf(hnew);
                short lo = f2bf(hnew - bf2f(hi));
                int row = 4 * lg + j;
                hfrag[wbuf][0][wm][c >> 3][row][c & 7] = hi;
                hfrag[wbuf][1][wm][c >> 3][row][c & 7] = lo;
            }
        }

        // ---- stage x for t+1 into xfrag[wbuf]
        if (t + 1 < SEQ) {
            #pragma unroll
            for (int it = 0; it < 2; ++it) {
                int q = tid + it * THREADS;
                int half = q >> 9, rem = q & 511;
                int chunk = rem >> 7, row16 = (rem >> 3) & 15, pos = rem & 7;
                int i = chunk * 8 + pos;
                int row = half * 16 + row16;
                float v = 0.0f;
                if (i < N_IN) v = x[(size_t)(rowbase + row) * (SEQ * N_IN) + (t + 1) * N_IN + i];
                short hi = f2bf(v);
                short lo = f2bf(v - bf2f(hi));
                xfrag[wbuf][0][half][chunk][row16][pos] = hi;
                xfrag[wbuf][1][half][chunk][row16][pos] = lo;
            }
        }
    }

    // ---- FC epilogue: out = h_last @ fc_w^T + fc_b
    __syncthreads();
    float* hfc = (float*)&hfrag[0][0][0][0][0][0];   // 32 KB scratch [32][256]
    #pragma unroll
    for (int s = 0; s < 4; ++s)
        #pragma unroll
        for (int j = 0; j < 4; ++j)
            hfc[(16 * wm + 4 * lg + j) * 256 + col[s]] = hold[s][j];
    __syncthreads();

    for (int p = tid; p < M_ROWS * N_OUT; p += THREADS) {
        int r = p / N_OUT, o = p - r * N_OUT;
        float acc = fc_b[o];
        #pragma unroll 4
        for (int k = 0; k < N_MID; ++k)
            acc = fmaf(hfc[r * 256 + k], fc_w[o * 256 + k], acc);
        out[(size_t)rowbase * N_OUT + p] = acc;
    }
}

extern "C" void kernel_launch(void* const* d_in, const int* in_sizes, int n_in,
                              void* d_out, int out_size, void* d_ws, size_t ws_size,
                              hipStream_t stream) {
    const float* x    = (const float*)d_in[0];
    const float* w_ih = (const float*)d_in[1];
    const float* w_hh = (const float*)d_in[2];
    const float* b_ih = (const float*)d_in[3];
    const float* b_hh = (const float*)d_in[4];
    const float* fc_w = (const float*)d_in[5];
    const float* fc_b = (const float*)d_in[6];
    float* out = (float*)d_out;

    short* wB = (short*)d_ws;                 // [768][256] bf16 = 384 KB
    short* wI = wB + G3 * N_MID;              // [768][32]  bf16 =  48 KB

    hipLaunchKernelGGL(prep_w, dim3(768), dim3(256), 0, stream, w_hh, w_ih, wB, wI);
    hipLaunchKernelGGL(gru_mfma, dim3(NBLK), dim3(THREADS), 0, stream,
                       x, wB, wI, b_ih, b_hh, fc_w, fc_b, out);
}

// Round 3
// 540.018 us; speedup vs baseline: 1.8090x; 1.8090x over previous
//
#include <hip/hip_runtime.h>
#include <hip/hip_bf16.h>
#include <math.h>

#define N_IN 28
#define N_MID 256
#define N_OUT 28
#define SEQ 28
#define BATCH 4096
#define THREADS 512
#define NBLOCKS 256
#define TEAM_ROWS 64
#define MEMBERS 4
#define HBUF_ELEMS (BATCH * N_MID)              // 1M uints per buffer = 4 MB
#define BAR_OFF (2ull * HBUF_ELEMS * 4ull)      // 8 MB

typedef __attribute__((ext_vector_type(8))) short bf16x8;
typedef __attribute__((ext_vector_type(4))) float f32x4;

#define MFMA(a, b, c) __builtin_amdgcn_mfma_f32_16x16x32_bf16((a), (b), (c), 0, 0, 0)

__device__ __forceinline__ short f2bf(float v) {
    __hip_bfloat16 b = __float2bfloat16(v);
    return *reinterpret_cast<short*>(&b);
}
__device__ __forceinline__ float bf2f(short s) {
    unsigned int u = ((unsigned int)(unsigned short)s) << 16;
    return __uint_as_float(u);
}
__device__ __forceinline__ float fsigmoid(float v) {
    return 1.0f / (1.0f + __expf(-v));
}
__device__ __forceinline__ float ftanh(float v) {
    float e = __expf(2.0f * v);
    return 1.0f - 2.0f / (e + 1.0f);
}

__global__ __launch_bounds__(THREADS, 2) void gru_team(
    const float* __restrict__ x,      // [B][T][28]
    const float* __restrict__ w_ih,   // [768][28]
    const float* __restrict__ w_hh,   // [768][256]
    const float* __restrict__ b_ih,
    const float* __restrict__ b_hh,
    const float* __restrict__ fc_w,   // [28][256]
    const float* __restrict__ fc_b,
    float* __restrict__ out,          // [B][28]
    unsigned int* __restrict__ hbuf,  // [2][4096][256] packed (hi | lo<<16)
    int* __restrict__ bar,            // [64] monotonic arrival counters
    int* __restrict__ gen)            // [64] completed-step generation
{
    // B-fragment-layout weight slice: [gate][col16grp][ks][col][k]  (96 KB)
    __shared__ short wlds[3][4][8][16][32];

    const int tid  = threadIdx.x;
    const int lane = tid & 63;
    const int l15  = lane & 15;
    const int lg   = lane >> 4;
    const int wv   = tid >> 6;   // 0..7
    const int wm   = wv >> 1;    // row quarter 0..3 (16 rows each)
    const int wn   = wv & 1;     // col half 0..1 (32 cols each)

    const int b        = blockIdx.x;
    const int xcd      = b & 7;
    const int slot     = b >> 3;
    const int member   = slot & 3;            // 0..3 -> col slice
    const int team     = xcd * 8 + (slot >> 2);  // 0..63, members co-XCD
    const int teambase = team * TEAM_ROWS;
    const int colbase  = member * 64;

    // ---- one-time: stage w_hh slice into LDS as B fragments (f32 -> bf16)
    for (int q = tid; q < 6144; q += THREADS) {
        int g   = q >> 11;
        int rem = q & 2047;
        int c4  = rem >> 9;  rem &= 511;
        int ks  = rem >> 6;  rem &= 63;
        int cl  = rem >> 2;
        int lgq = rem & 3;
        int grow = g * 256 + colbase + c4 * 16 + cl;
        const float* src = w_hh + (size_t)grow * 256 + ks * 32 + lgq * 8;
        float4 v0 = *(const float4*)src;
        float4 v1 = *(const float4*)(src + 4);
        bf16x8 d;
        d[0] = f2bf(v0.x); d[1] = f2bf(v0.y); d[2] = f2bf(v0.z); d[3] = f2bf(v0.w);
        d[4] = f2bf(v1.x); d[5] = f2bf(v1.y); d[6] = f2bf(v1.z); d[7] = f2bf(v1.w);
        *(bf16x8*)&wlds[g][c4][ks][cl][lgq * 8] = d;
    }

    // ---- one-time: w_ih B-frags in registers (K=32, zero-padded), biases
    bf16x8 bI[3][2];
    float  biasR[2], biasZ[2], biasIN[2], biasHN[2];
    int    colA[2];
    #pragma unroll
    for (int a = 0; a < 2; ++a) {
        int c = colbase + wn * 32 + a * 16 + l15;
        colA[a]   = c;
        biasR[a]  = b_ih[c]       + b_hh[c];
        biasZ[a]  = b_ih[256 + c] + b_hh[256 + c];
        biasIN[a] = b_ih[512 + c];
        biasHN[a] = b_hh[512 + c];
        #pragma unroll
        for (int g = 0; g < 3; ++g) {
            int grow = g * 256 + c;
            bf16x8 d;
            #pragma unroll
            for (int e = 0; e < 8; ++e) {
                int k = lg * 8 + e;
                float v = (k < N_IN) ? w_ih[grow * N_IN + k] : 0.0f;
                d[e] = f2bf(v);
            }
            bI[g][a] = d;
        }
    }

    float hold[2][4];
    #pragma unroll
    for (int a = 0; a < 2; ++a)
        #pragma unroll
        for (int j = 0; j < 4; ++j) hold[a][j] = 0.0f;

    __syncthreads();

    const int arow = teambase + wm * 16 + l15;   // A-fragment row (x and h)

    for (int t = 0; t < SEQ; ++t) {
        // ---- x A-fragment (hi/lo), h-independent: overlaps stragglers
        const float* xp = x + (size_t)arow * (SEQ * N_IN) + t * N_IN + lg * 8;
        float xv[8];
        if (lg < 3) {
            float4 a0 = *(const float4*)xp;
            float4 a1 = *(const float4*)(xp + 4);
            xv[0] = a0.x; xv[1] = a0.y; xv[2] = a0.z; xv[3] = a0.w;
            xv[4] = a1.x; xv[5] = a1.y; xv[6] = a1.z; xv[7] = a1.w;
        } else {
            float4 a0 = *(const float4*)xp;   // k = 24..27
            xv[0] = a0.x; xv[1] = a0.y; xv[2] = a0.z; xv[3] = a0.w;
            xv[4] = 0.0f; xv[5] = 0.0f; xv[6] = 0.0f; xv[7] = 0.0f;
        }
        bf16x8 xh, xl;
        #pragma unroll
        for (int e = 0; e < 8; ++e) {
            short h = f2bf(xv[e]);
            xh[e] = h;
            xl[e] = f2bf(xv[e] - bf2f(h));
        }

        f32x4 aR[2], aZ[2], aIN[2], aHN[2];
        #pragma unroll
        for (int a = 0; a < 2; ++a) {
            aR[a]  = (f32x4){biasR[a],  biasR[a],  biasR[a],  biasR[a]};
            aZ[a]  = (f32x4){biasZ[a],  biasZ[a],  biasZ[a],  biasZ[a]};
            aIN[a] = (f32x4){biasIN[a], biasIN[a], biasIN[a], biasIN[a]};
            aHN[a] = (f32x4){biasHN[a], biasHN[a], biasHN[a], biasHN[a]};
        }

        // input projection (register B-frags, no LDS/global dependency)
        #pragma unroll
        for (int a = 0; a < 2; ++a) {
            aR[a]  = MFMA(xh, bI[0][a], aR[a]);  aR[a]  = MFMA(xl, bI[0][a], aR[a]);
            aZ[a]  = MFMA(xh, bI[1][a], aZ[a]);  aZ[a]  = MFMA(xl, bI[1][a], aZ[a]);
            aIN[a] = MFMA(xh, bI[2][a], aIN[a]); aIN[a] = MFMA(xl, bI[2][a], aIN[a]);
        }

        // ---- wait for teammates' h(t)
        if (t > 0) {
            if (tid == 0) {
                while (__hip_atomic_load(&gen[team], __ATOMIC_ACQUIRE,
                                         __HIP_MEMORY_SCOPE_AGENT) < t)
                    __builtin_amdgcn_s_sleep(2);
            }
            __syncthreads();
        }

        // ---- hidden projection: h from L2 double-buffer, w from LDS
        const unsigned int* hrd =
            hbuf + (size_t)(t & 1) * HBUF_ELEMS + (size_t)arow * N_MID;
        #pragma unroll
        for (int ks = 0; ks < 8; ++ks) {
            uint4 p0 = *(const uint4*)(hrd + ks * 32 + lg * 8);
            uint4 p1 = *(const uint4*)(hrd + ks * 32 + lg * 8 + 4);
            unsigned int u[8];
            *(uint4*)&u[0] = p0;
            *(uint4*)&u[4] = p1;
            bf16x8 ah, al;
            #pragma unroll
            for (int e = 0; e < 8; ++e) {
                ah[e] = (short)(u[e] & 0xffffu);
                al[e] = (short)(u[e] >> 16);
            }
            #pragma unroll
            for (int a = 0; a < 2; ++a) {
                const int c4 = wn * 2 + a;
                bf16x8 b0 = *(const bf16x8*)&wlds[0][c4][ks][l15][lg * 8];
                aR[a] = MFMA(ah, b0, aR[a]);   aR[a] = MFMA(al, b0, aR[a]);
                bf16x8 b1 = *(const bf16x8*)&wlds[1][c4][ks][l15][lg * 8];
                aZ[a] = MFMA(ah, b1, aZ[a]);   aZ[a] = MFMA(al, b1, aZ[a]);
                bf16x8 b2 = *(const bf16x8*)&wlds[2][c4][ks][l15][lg * 8];
                aHN[a] = MFMA(ah, b2, aHN[a]); aHN[a] = MFMA(al, b2, aHN[a]);
            }
        }

        // ---- lane-local GRU update; store packed h(t+1)
        unsigned int* hwr = hbuf + (size_t)((t + 1) & 1) * HBUF_ELEMS;
        #pragma unroll
        for (int a = 0; a < 2; ++a) {
            #pragma unroll
            for (int j = 0; j < 4; ++j) {
                float r = fsigmoid(aR[a][j]);
                float z = fsigmoid(aZ[a][j]);
                float n = ftanh(aIN[a][j] + r * aHN[a][j]);
                float hnew = (1.0f - z) * n + z * hold[a][j];
                hold[a][j] = hnew;
                short hi = f2bf(hnew);
                short lo = f2bf(hnew - bf2f(hi));
                int row = teambase + wm * 16 + lg * 4 + j;
                hwr[(size_t)row * N_MID + colA[a]] =
                    (unsigned int)(unsigned short)hi |
                    ((unsigned int)(unsigned short)lo << 16);
            }
        }

        __syncthreads();   // drains all waves' stores (vmcnt 0 before s_barrier)
        if (tid == 0) {
            int prev = __hip_atomic_fetch_add(&bar[team], 1, __ATOMIC_ACQ_REL,
                                              __HIP_MEMORY_SCOPE_AGENT);
            if (prev == MEMBERS * (t + 1) - 1)
                __hip_atomic_store(&gen[team], t + 1, __ATOMIC_RELEASE,
                                   __HIP_MEMORY_SCOPE_AGENT);
        }
        __syncthreads();
    }

    // ---- FC epilogue: this block handles rows [teambase + member*16, +16)
    if (tid == 0) {
        while (__hip_atomic_load(&gen[team], __ATOMIC_ACQUIRE,
                                 __HIP_MEMORY_SCOPE_AGENT) < SEQ)
            __builtin_amdgcn_s_sleep(2);
    }
    __syncthreads();

    float* hfc = (float*)&wlds[0][0][0][0][0];     // reuse 16 KB of LDS
    const unsigned int* hL = hbuf;                  // buf 0 holds h(SEQ)
    for (int q = tid; q < 16 * N_MID; q += THREADS) {
        int rl = q >> 8, k = q & 255;
        unsigned int u = hL[(size_t)(teambase + member * 16 + rl) * N_MID + k];
        hfc[q] = bf2f((short)(u & 0xffffu)) + bf2f((short)(u >> 16));
    }
    __syncthreads();
    if (tid < 16 * N_OUT) {
        int rl = tid / N_OUT, o = tid - rl * N_OUT;
        float acc = fc_b[o];
        #pragma unroll 8
        for (int k = 0; k < N_MID; ++k)
            acc = fmaf(hfc[rl * 256 + k], fc_w[o * 256 + k], acc);
        out[(size_t)(teambase + member * 16 + rl) * N_OUT + o] = acc;
    }
}

extern "C" void kernel_launch(void* const* d_in, const int* in_sizes, int n_in,
                              void* d_out, int out_size, void* d_ws, size_t ws_size,
                              hipStream_t stream) {
    const float* x    = (const float*)d_in[0];
    const float* w_ih = (const float*)d_in[1];
    const float* w_hh = (const float*)d_in[2];
    const float* b_ih = (const float*)d_in[3];
    const float* b_hh = (const float*)d_in[4];
    const float* fc_w = (const float*)d_in[5];
    const float* fc_b = (const float*)d_in[6];
    float* out = (float*)d_out;

    unsigned int* hbuf = (unsigned int*)d_ws;
    int* bar = (int*)((char*)d_ws + BAR_OFF);
    int* gen = bar + 64;

    // h(0) = 0 (buf 0); barrier counters/generations = 0 — every launch.
    hipMemsetAsync(d_ws, 0, (size_t)HBUF_ELEMS * 4, stream);
    hipMemsetAsync((char*)d_ws + BAR_OFF, 0, 512, stream);

    hipLaunchKernelGGL(gru_team, dim3(NBLOCKS), dim3(THREADS), 0, stream,
                       x, w_ih, w_hh, b_ih, b_hh, fc_w, fc_b, out, hbuf, bar, gen);
}

// Round 4
// 155.595 us; speedup vs baseline: 6.2786x; 3.4707x over previous
//
#include <hip/hip_runtime.h>
#include <hip/hip_bf16.h>
#include <math.h>

#define N_IN 28
#define N_MID 256
#define N_OUT 28
#define SEQ 28
#define BATCH 4096
#define G3 768
#define ROWS 16
#define THREADS 512
#define NBLK (BATCH / ROWS)   // 256

typedef __attribute__((ext_vector_type(8))) short bf16x8;
typedef __attribute__((ext_vector_type(4))) float f32x4;

#define MFMA(a, b, c) __builtin_amdgcn_mfma_f32_16x16x32_bf16((a), (b), (c), 0, 0, 0)

__device__ __forceinline__ short f2bf(float v) {
    __hip_bfloat16 b = __float2bfloat16(v);
    return *reinterpret_cast<short*>(&b);
}
__device__ __forceinline__ float bf2f(short s) {
    unsigned int u = ((unsigned int)(unsigned short)s) << 16;
    return __uint_as_float(u);
}
__device__ __forceinline__ float fsigmoid(float v) {
    return 1.0f / (1.0f + __expf(-v));
}
__device__ __forceinline__ float ftanh(float v) {
    float e = __expf(2.0f * v);
    return 1.0f - 2.0f / (e + 1.0f);
}

// prep: w_hh [768][256] f32 -> wB bf16; w_ih [768][28] -> wI bf16 [768][32] padded
__global__ void prep_w(const float* __restrict__ w_hh, const float* __restrict__ w_ih,
                       short* __restrict__ wB, short* __restrict__ wI) {
    int idx = blockIdx.x * 256 + threadIdx.x;
    if (idx < G3 * N_MID) wB[idx] = f2bf(w_hh[idx]);
    if (idx < G3 * 32) {
        int g = idx >> 5, k = idx & 31;
        float v = (k < N_IN) ? w_ih[g * N_IN + k] : 0.0f;
        wI[idx] = f2bf(v);
    }
}

__global__ __launch_bounds__(THREADS, 2) void gru_onecu(
    const float* __restrict__ x,     // [B][T][28]
    const short* __restrict__ wB,    // [768][256] bf16
    const short* __restrict__ wI,    // [768][32] bf16
    const float* __restrict__ b_ih,
    const float* __restrict__ b_hh,
    const float* __restrict__ fc_w,  // [28][256]
    const float* __restrict__ fc_b,
    float* __restrict__ out)         // [B][28]
{
    // Weight K-slices 6,7 as frag-linear B-fragments: [ksl][gate][cg][lane][8] (96 KB)
    __shared__ short wlds[2][3][16][64][8];
    // h double-buffer A-fragments: [buf][prec][kchunk][row(pad 17)][pos] (34 KB)
    __shared__ short hl[2][2][32][17][8];

    const int tid  = threadIdx.x;
    const int lane = tid & 63;
    const int l15  = lane & 15;
    const int lg   = lane >> 4;
    const int wv   = tid >> 6;              // 0..7: wave owns cols [32wv, 32wv+32)
    const int rowbase = blockIdx.x * ROWS;

    // ---- one-time: stage K-slices 6,7 into LDS (frag-linear, conflict-free)
    for (int idx = tid; idx < 2 * 3 * 16 * 64; idx += THREADS) {
        int L    = idx & 63;
        int frag = idx >> 6;              // 0..95
        int ksl  = frag / 48;
        int rem  = frag - ksl * 48;
        int g    = rem >> 4;
        int cg   = rem & 15;
        int col  = cg * 16 + (L & 15);
        int k0   = (6 + ksl) * 32 + (L >> 4) * 8;
        *(bf16x8*)&wlds[ksl][g][cg][L][0] =
            *(const bf16x8*)(wB + ((size_t)(g * 256 + col)) * 256 + k0);
    }

    // ---- one-time: K-slices 0..5 into registers (static-indexed), w_ih, biases
    bf16x8 wreg[3][2][6];
    bf16x8 wireg[3][2];
    int   colA[2];
    float bRv[2], bZv[2], bINv[2], bHNv[2];
    #pragma unroll
    for (int a = 0; a < 2; ++a) {
        int c = wv * 32 + a * 16 + l15;
        colA[a] = c;
        bRv[a]  = b_ih[c]       + b_hh[c];
        bZv[a]  = b_ih[256 + c] + b_hh[256 + c];
        bINv[a] = b_ih[512 + c];
        bHNv[a] = b_hh[512 + c];
        #pragma unroll
        for (int g = 0; g < 3; ++g) {
            wireg[g][a] = *(const bf16x8*)(wI + ((size_t)(g * 256 + c)) * 32 + lg * 8);
            #pragma unroll
            for (int ks = 0; ks < 6; ++ks)
                wreg[g][a][ks] =
                    *(const bf16x8*)(wB + ((size_t)(g * 256 + c)) * 256 + ks * 32 + lg * 8);
        }
    }

    float hold[2][4];
    #pragma unroll
    for (int a = 0; a < 2; ++a)
        #pragma unroll
        for (int j = 0; j < 4; ++j) hold[a][j] = 0.0f;

    __syncthreads();

    for (int t = 0; t < SEQ; ++t) {
        const int rb = t & 1, wb = rb ^ 1;

        // ---- x A-fragment (row = rowbase + l15, k-octet = lg)
        const float* xp = x + (size_t)(rowbase + l15) * (SEQ * N_IN) + t * N_IN + lg * 8;
        float xv[8];
        if (lg < 3) {
            float4 a0 = *(const float4*)xp;
            float4 a1 = *(const float4*)(xp + 4);
            xv[0] = a0.x; xv[1] = a0.y; xv[2] = a0.z; xv[3] = a0.w;
            xv[4] = a1.x; xv[5] = a1.y; xv[6] = a1.z; xv[7] = a1.w;
        } else {
            float4 a0 = *(const float4*)xp;
            xv[0] = a0.x; xv[1] = a0.y; xv[2] = a0.z; xv[3] = a0.w;
            xv[4] = 0.0f; xv[5] = 0.0f; xv[6] = 0.0f; xv[7] = 0.0f;
        }
        bf16x8 xh, xl;
        #pragma unroll
        for (int e = 0; e < 8; ++e) {
            short h = f2bf(xv[e]);
            xh[e] = h;
            xl[e] = f2bf(xv[e] - bf2f(h));
        }

        f32x4 aR[2], aZ[2], aIN[2], aHN[2];
        #pragma unroll
        for (int a = 0; a < 2; ++a) {
            aR[a]  = (f32x4){bRv[a],  bRv[a],  bRv[a],  bRv[a]};
            aZ[a]  = (f32x4){bZv[a],  bZv[a],  bZv[a],  bZv[a]};
            aIN[a] = (f32x4){bINv[a], bINv[a], bINv[a], bINv[a]};
            aHN[a] = (f32x4){bHNv[a], bHNv[a], bHNv[a], bHNv[a]};
        }

        // ---- input projection (register B-frags)
        #pragma unroll
        for (int a = 0; a < 2; ++a) {
            aR[a]  = MFMA(xh, wireg[0][a], aR[a]);  aR[a]  = MFMA(xl, wireg[0][a], aR[a]);
            aZ[a]  = MFMA(xh, wireg[1][a], aZ[a]);  aZ[a]  = MFMA(xl, wireg[1][a], aZ[a]);
            aIN[a] = MFMA(xh, wireg[2][a], aIN[a]); aIN[a] = MFMA(xl, wireg[2][a], aIN[a]);
        }

        // ---- hidden projection (skip at t=0: h=0)
        if (t > 0) {
            // K-slices 0..5: B from registers
            #pragma unroll
            for (int ks = 0; ks < 6; ++ks) {
                bf16x8 ah = *(const bf16x8*)&hl[rb][0][ks * 4 + lg][l15][0];
                bf16x8 al = *(const bf16x8*)&hl[rb][1][ks * 4 + lg][l15][0];
                #pragma unroll
                for (int a = 0; a < 2; ++a) {
                    aR[a]  = MFMA(ah, wreg[0][a][ks], aR[a]);
                    aR[a]  = MFMA(al, wreg[0][a][ks], aR[a]);
                    aZ[a]  = MFMA(ah, wreg[1][a][ks], aZ[a]);
                    aZ[a]  = MFMA(al, wreg[1][a][ks], aZ[a]);
                    aHN[a] = MFMA(ah, wreg[2][a][ks], aHN[a]);
                    aHN[a] = MFMA(al, wreg[2][a][ks], aHN[a]);
                }
            }
            // K-slices 6,7: B from LDS
            #pragma unroll
            for (int ksl = 0; ksl < 2; ++ksl) {
                const int ks = 6 + ksl;
                bf16x8 ah = *(const bf16x8*)&hl[rb][0][ks * 4 + lg][l15][0];
                bf16x8 al = *(const bf16x8*)&hl[rb][1][ks * 4 + lg][l15][0];
                #pragma unroll
                for (int a = 0; a < 2; ++a) {
                    const int cg = 2 * wv + a;
                    bf16x8 b0 = *(const bf16x8*)&wlds[ksl][0][cg][lane][0];
                    aR[a]  = MFMA(ah, b0, aR[a]);   aR[a]  = MFMA(al, b0, aR[a]);
                    bf16x8 b1 = *(const bf16x8*)&wlds[ksl][1][cg][lane][0];
                    aZ[a]  = MFMA(ah, b1, aZ[a]);   aZ[a]  = MFMA(al, b1, aZ[a]);
                    bf16x8 b2 = *(const bf16x8*)&wlds[ksl][2][cg][lane][0];
                    aHN[a] = MFMA(ah, b2, aHN[a]);  aHN[a] = MFMA(al, b2, aHN[a]);
                }
            }
        }

        // ---- lane-local GRU update; write h(t+1) A-frags to other buffer
        #pragma unroll
        for (int a = 0; a < 2; ++a) {
            const int c = colA[a];
            #pragma unroll
            for (int j = 0; j < 4; ++j) {
                float r = fsigmoid(aR[a][j]);
                float z = fsigmoid(aZ[a][j]);
                float n = ftanh(aIN[a][j] + r * aHN[a][j]);
                float hnew = (1.0f - z) * n + z * hold[a][j];
                hold[a][j] = hnew;
                short hi = f2bf(hnew);
                short lo = f2bf(hnew - bf2f(hi));
                hl[wb][0][c >> 3][4 * lg + j][c & 7] = hi;
                hl[wb][1][c >> 3][4 * lg + j][c & 7] = lo;
            }
        }
        __syncthreads();
    }

    // ---- FC epilogue: h(SEQ) is in buf 0 (SEQ even)
    float* hf = (float*)&wlds[0][0][0][0][0];   // overlay 16 KB on weight LDS
    {
        int r = tid >> 5, kg = tid & 31;
        #pragma unroll
        for (int e = 0; e < 8; ++e) {
            int k = kg * 8 + e;
            hf[r * 256 + k] = bf2f(hl[0][0][k >> 3][r][k & 7]) +
                              bf2f(hl[0][1][k >> 3][r][k & 7]);
        }
    }
    __syncthreads();
    if (tid < ROWS * N_OUT) {
        int r = tid / N_OUT, o = tid - r * N_OUT;
        float acc = fc_b[o];
        #pragma unroll
        for (int k4 = 0; k4 < 64; ++k4) {
            float4 hv = *(const float4*)&hf[r * 256 + k4 * 4];
            float4 wv4 = *(const float4*)&fc_w[o * 256 + k4 * 4];
            acc = fmaf(hv.x, wv4.x, acc);
            acc = fmaf(hv.y, wv4.y, acc);
            acc = fmaf(hv.z, wv4.z, acc);
            acc = fmaf(hv.w, wv4.w, acc);
        }
        out[(size_t)(rowbase + r) * N_OUT + o] = acc;
    }
}

extern "C" void kernel_launch(void* const* d_in, const int* in_sizes, int n_in,
                              void* d_out, int out_size, void* d_ws, size_t ws_size,
                              hipStream_t stream) {
    const float* x    = (const float*)d_in[0];
    const float* w_ih = (const float*)d_in[1];
    const float* w_hh = (const float*)d_in[2];
    const float* b_ih = (const float*)d_in[3];
    const float* b_hh = (const float*)d_in[4];
    const float* fc_w = (const float*)d_in[5];
    const float* fc_b = (const float*)d_in[6];
    float* out = (float*)d_out;

    short* wB = (short*)d_ws;                 // [768][256] bf16 = 384 KB
    short* wI = wB + G3 * N_MID;              // [768][32]  bf16 =  48 KB

    hipLaunchKernelGGL(prep_w, dim3(768), dim3(256), 0, stream, w_hh, w_ih, wB, wI);
    hipLaunchKernelGGL(gru_onecu, dim3(NBLK), dim3(THREADS), 0, stream,
                       x, wB, wI, b_ih, b_hh, fc_w, fc_b, out);
}